// Round 5
// baseline (146.653 us; speedup 1.0000x reference)
//
#include <hip/hip_runtime.h>
#include <hip/hip_bf16.h>

// KAN linear == GEMM M=8192, N=512, K=4096 (8 Chebyshev/silu feats per input,
// basis_0 folded into bias). Round 14: R12 (occupancy) and R13 (bank
// conflicts, B-traffic) both null => limiter is the 2-phase
// stage->vmcnt(0)->barrier structure itself (__syncthreads drains the
// just-issued DMA every iter; m233/m218). R14 keeps R13's verified math and
// replaces the sync: counted vmcnt (never 0 in loop) + raw s_barrier, so the
// B-DMA for it+1 stays in flight across compute(it). x staging moves from LDS
// to a 2-deep per-lane register ring (wave kk only needs its own 4 cols =
// one aligned float4 per token-group): exactly 6 vmcnt ops/iter ->
// deterministic counts: vmcnt(6) before gen-consume, vmcnt(2)+lgkm(0) before
// barrier. T5 setprio around the 8-MFMA cluster. LDS = Bs dbuf only.
#define IN_FEAT 512
#define OUT_FEAT 512
#define NTOK 8192
#define KDIM 4096

typedef short bf16x8 __attribute__((ext_vector_type(8)));
typedef float f32x16 __attribute__((ext_vector_type(16)));

static __device__ inline short f2bf(float f) {
    union { float f; unsigned u; } v; v.f = f;
    unsigned u = v.u;
    u += 0x7fffu + ((u >> 16) & 1u);   // RNE
    return (short)(u >> 16);
}

static __device__ inline unsigned pack2bf(float f0, float f1) {
    union { float f; unsigned u; } a, b; a.f = f0; b.f = f1;
    return __builtin_amdgcn_perm(b.u + 0x8000u, a.u + 0x8000u, 0x07060302u);
}

// 8 basis features of one (token,input): [silu(xc), xc, T2..T7]
static __device__ inline bf16x8 gen_chunk(float xv) {
    float xc = fminf(fmaxf(xv, -1.f), 1.f);
    float e  = __expf(-xc);
    float bse = xc * __builtin_amdgcn_rcpf(1.f + e);
    float b2 = 2.f * xc * xc - 1.f;
    float b3 = 2.f * xc * b2 - 1.f;
    float b4 = 2.f * xc * b3 - 1.f;
    float b5 = 2.f * xc * b4 - 1.f;
    float b6 = 2.f * xc * b5 - 1.f;
    float b7 = 2.f * xc * b6 - 1.f;
    union { uint4 u; bf16x8 v; } r;
    r.u.x = pack2bf(bse, xc);
    r.u.y = pack2bf(b2, b3);
    r.u.z = pack2bf(b4, b5);
    r.u.w = pack2bf(b6, b7);
    return r.v;
}

static __device__ inline void gload_lds16(const short* g, short* l) {
    __builtin_amdgcn_global_load_lds(
        (const __attribute__((address_space(1))) unsigned int*)g,
        (__attribute__((address_space(3))) unsigned int*)l,
        16, 0, 0);
}

// ---------------- prep: W bf16 [512 x 4096] + folded bias ----------------
__global__ __launch_bounds__(256) void kan_prep(
    const float* __restrict__ coeff, const float* __restrict__ scale_base,
    const float* __restrict__ scale_spline, const float* __restrict__ base_bias,
    short* __restrict__ Wb, float* __restrict__ bias)
{
    int o = blockIdx.x;
    int tid = threadIdx.x;
    float local = 0.f;
#pragma unroll
    for (int rep = 0; rep < 2; ++rep) {
        int i = tid + rep * 256;
        size_t oi = (size_t)o * IN_FEAT + i;
        const float4* c4 = (const float4*)(coeff + oi * 8);
        float4 ca = c4[0], cb = c4[1];
        float ss = scale_spline[oi];
        float sb = scale_base[oi];
        local += base_bias[oi] + ss * ca.x;
        bf16x8 w;
        w[0] = f2bf(sb);
        w[1] = f2bf(ss * ca.y); w[2] = f2bf(ss * ca.z); w[3] = f2bf(ss * ca.w);
        w[4] = f2bf(ss * cb.x); w[5] = f2bf(ss * cb.y); w[6] = f2bf(ss * cb.z);
        w[7] = f2bf(ss * cb.w);
        *(bf16x8*)(Wb + (size_t)o * KDIM + (size_t)i * 8) = w;
    }
    __shared__ float red[4];
    for (int off = 32; off > 0; off >>= 1) local += __shfl_down(local, off, 64);
    int lane = tid & 63, wv = tid >> 6;
    if (lane == 0) red[wv] = local;
    __syncthreads();
    if (tid == 0) bias[o] = red[0] + red[1] + red[2] + red[3];
}

// --- 32x32x16 fused GEMM, 64m x 64n, 4-way split-K, counted-vmcnt pipeline ---
__global__ __launch_bounds__(256, 3) void kan_gemm14(
    const float* __restrict__ x, const short* __restrict__ Wb,
    const float* __restrict__ bias, float* __restrict__ out)
{
    // LDS 40960 B: Bs dbuf [2][64 rows][16 slots][8 shorts] = 32 KB
    // (phys slot = clog ^ (row&15), as R13); tail 8 KB only for the epilogue
    // reduce slabs (rbuf overlays the whole pool).
    __shared__ __align__(16) short POOL[20480];
    short* Bs = POOL;                     // [2][8192]

    int tid = threadIdx.x;
    int nb = blockIdx.x & 7;         // XCD j sees nb=j -> 0.5 MB W slice per XCD L2
    int mb = blockIdx.x >> 3;        // 128 m-tiles
    int m0 = mb * 64, o0 = nb * 64;

    int lane = tid & 63, wv = tid >> 6;
    int kk = wv;                     // wave = 64m x 64n on K-quarter kk
    int l31 = lane & 31, half = lane >> 5;
    int rm  = l31 & 15;

    f32x16 acc[2][2];                // [fm][fn], 32x32 each
#pragma unroll
    for (int a = 0; a < 2; ++a)
#pragma unroll
        for (int b = 0; b < 2; ++b) acc[a][b] = (f32x16)0.f;

    // B DMA pointers (verbatim R13): wave wv stages rows [wv*16,+16), 4 calls.
    int rl = lane >> 4, q = lane & 15;
    const short* pB0 = Wb + (size_t)(o0 + wv * 16 +  0 + rl) * KDIM + (size_t)(q ^ ( 0 + rl)) * 8;
    const short* pB1 = Wb + (size_t)(o0 + wv * 16 +  4 + rl) * KDIM + (size_t)(q ^ ( 4 + rl)) * 8;
    const short* pB2 = Wb + (size_t)(o0 + wv * 16 +  8 + rl) * KDIM + (size_t)(q ^ ( 8 + rl)) * 8;
    const short* pB3 = Wb + (size_t)(o0 + wv * 16 + 12 + rl) * KDIM + (size_t)(q ^ (12 + rl)) * 8;

    // x: wave kk consumes only cols [kk*4, kk*4+4) of each 16-col K-block ->
    // one aligned float4 per token-group per iter, straight to registers.
    // token group 0: rows m0+l31; group 1: rows m0+32+l31 (xp0 + 16384 floats).
    const float* xp0 = x + (size_t)(m0 + l31) * IN_FEAT + kk * 4;

    // Constant frag-read offsets (shorts): col s0 = kk*4+half, s1 = s0+2.
    int s0 = kk * 4 + half, s1 = s0 + 2;
    int of00 = l31 * 128        + ((s0 ^ rm) * 8);
    int of01 = (32 + l31) * 128 + ((s0 ^ rm) * 8);
    int of10 = l31 * 128        + ((s1 ^ rm) * 8);
    int of11 = (32 + l31) * 128 + ((s1 ^ rm) * 8);

#define COMPUTE(CUR, P0, P1)                                                  \
    {                                                                         \
        const short* Bsc_ = Bs + (CUR) * 8192;                                \
        bf16x8 b00 = *(const bf16x8*)(Bsc_ + of00);                           \
        bf16x8 b01 = *(const bf16x8*)(Bsc_ + of01);                           \
        bf16x8 b10 = *(const bf16x8*)(Bsc_ + of10);                           \
        bf16x8 b11 = *(const bf16x8*)(Bsc_ + of11);                           \
        bf16x8 a00 = gen_chunk(half ? (P0).y : (P0).x);                       \
        bf16x8 a01 = gen_chunk(half ? (P1).y : (P1).x);                       \
        bf16x8 a10 = gen_chunk(half ? (P0).w : (P0).z);                       \
        bf16x8 a11 = gen_chunk(half ? (P1).w : (P1).z);                       \
        __builtin_amdgcn_s_setprio(1);                                        \
        acc[0][0] = __builtin_amdgcn_mfma_f32_32x32x16_bf16(a00, b00, acc[0][0], 0, 0, 0); \
        acc[0][1] = __builtin_amdgcn_mfma_f32_32x32x16_bf16(a00, b01, acc[0][1], 0, 0, 0); \
        acc[1][0] = __builtin_amdgcn_mfma_f32_32x32x16_bf16(a01, b00, acc[1][0], 0, 0, 0); \
        acc[1][1] = __builtin_amdgcn_mfma_f32_32x32x16_bf16(a01, b01, acc[1][1], 0, 0, 0); \
        acc[0][0] = __builtin_amdgcn_mfma_f32_32x32x16_bf16(a10, b10, acc[0][0], 0, 0, 0); \
        acc[0][1] = __builtin_amdgcn_mfma_f32_32x32x16_bf16(a10, b11, acc[0][1], 0, 0, 0); \
        acc[1][0] = __builtin_amdgcn_mfma_f32_32x32x16_bf16(a11, b10, acc[1][0], 0, 0, 0); \
        acc[1][1] = __builtin_amdgcn_mfma_f32_32x32x16_bf16(a11, b11, acc[1][1], 0, 0, 0); \
        __builtin_amdgcn_s_setprio(0);                                        \
    }

    // Pipeline invariant at top of iter it (post-barrier): outstanding vmem =
    // x(it) [2 float4]. (a) +B(it+1)[4 gload_lds] +x(it+1)[2] -> <=8, in issue
    // order [x(it), B(it+1), x(it+1)].  vmcnt(6) drains x(it);
    // vmcnt(2) drains B(it+1) (x(it+1) stays in flight across the barrier).
#define ITER(IT, CUR, PC0, PC1, PN0, PN1)                                     \
    {                                                                         \
        short* bd_ = Bs + ((CUR) ^ 1) * 8192 + wv * 2048;                     \
        const size_t bo_ = (size_t)((IT) + 1) * 128;                          \
        gload_lds16(pB0 + bo_, bd_);                                          \
        gload_lds16(pB1 + bo_, bd_ + 512);                                    \
        gload_lds16(pB2 + bo_, bd_ + 1024);                                   \
        gload_lds16(pB3 + bo_, bd_ + 1536);                                   \
        __builtin_amdgcn_sched_barrier(0);                                    \
        asm volatile("" ::: "memory");                                        \
        {                                                                     \
            const float* xq_ = xp0 + (size_t)((IT) + 1) * 16;                 \
            PN0 = *(const float4*)(xq_);                                      \
            PN1 = *(const float4*)(xq_ + 16384);                              \
        }                                                                     \
        __builtin_amdgcn_sched_barrier(0);                                    \
        asm volatile("s_waitcnt vmcnt(6)" ::: "memory");                      \
        __builtin_amdgcn_sched_barrier(0);                                    \
        COMPUTE(CUR, PC0, PC1);                                               \
        asm volatile("s_waitcnt vmcnt(2) lgkmcnt(0)" ::: "memory");           \
        __builtin_amdgcn_s_barrier();                                         \
        asm volatile("" ::: "memory");                                        \
    }

    float4 Pa0, Pa1, Pb0, Pb1;

    // ---- prologue: B(0) -> buf0, x(0) -> pend set a; publish buf0 ----
    {
        short* bd_ = Bs + wv * 2048;
        gload_lds16(pB0, bd_);
        gload_lds16(pB1, bd_ + 512);
        gload_lds16(pB2, bd_ + 1024);
        gload_lds16(pB3, bd_ + 1536);
        __builtin_amdgcn_sched_barrier(0);
        asm volatile("" ::: "memory");
        Pa0 = *(const float4*)(xp0);
        Pa1 = *(const float4*)(xp0 + 16384);
        __builtin_amdgcn_sched_barrier(0);
        asm volatile("s_waitcnt vmcnt(2)" ::: "memory");
        __builtin_amdgcn_s_barrier();
        asm volatile("" ::: "memory");
    }

    // ---- main: iters 0..30 pipelined; x(k) lives in pend set (k&1) ----
    for (int j = 0; j < 15; ++j) {
        ITER(2 * j,     0, Pa0, Pa1, Pb0, Pb1);
        ITER(2 * j + 1, 1, Pb0, Pb1, Pa0, Pa1);
    }
    ITER(30, 0, Pa0, Pa1, Pb0, Pb1);

    // ---- peeled iter 31: nothing left to stage ----
    asm volatile("s_waitcnt vmcnt(0)" ::: "memory");
    __builtin_amdgcn_sched_barrier(0);
    COMPUTE(1, Pb0, Pb1);
#undef ITER
#undef COMPUTE

    // ---- epilogue: 4-way split-K reduce through LDS (verbatim R13) ----
    float* rbuf = (float*)POOL;      // 10240 floats; max used 4224+4221 = 8445
    __syncthreads();                 // everyone done with Bs
    if (kk >= 2) {                   // kk=2 -> slab 0, kk=3 -> slab 1
        float* s_ = rbuf + (size_t)(kk - 2) * 4224 + lane * 66;
#pragma unroll
        for (int fm = 0; fm < 2; ++fm)
#pragma unroll
            for (int fn = 0; fn < 2; ++fn)
#pragma unroll
                for (int r = 0; r < 16; ++r)
                    s_[(fm * 2 + fn) * 16 + r] = acc[fm][fn][r];
    }
    __syncthreads();
    if (kk < 2) {                    // kk0 += kk2, kk1 += kk3
        const float* s_ = rbuf + (size_t)kk * 4224 + lane * 66;
#pragma unroll
        for (int fm = 0; fm < 2; ++fm)
#pragma unroll
            for (int fn = 0; fn < 2; ++fn)
#pragma unroll
                for (int r = 0; r < 16; ++r)
                    acc[fm][fn][r] += s_[(fm * 2 + fn) * 16 + r];
    }
    __syncthreads();
    if (kk == 1) {                   // kk1 partial -> slab 0
        float* s_ = rbuf + lane * 66;
#pragma unroll
        for (int fm = 0; fm < 2; ++fm)
#pragma unroll
            for (int fn = 0; fn < 2; ++fn)
#pragma unroll
                for (int r = 0; r < 16; ++r)
                    s_[(fm * 2 + fn) * 16 + r] = acc[fm][fn][r];
    }
    __syncthreads();
    if (kk == 0) {
        const float* s_ = rbuf + lane * 66;
        // C/D layout (32x32): col = lane&31, row = (r&3) + 8*(r>>2) + 4*(lane>>5)
#pragma unroll
        for (int fn = 0; fn < 2; ++fn) {
            int o = o0 + fn * 32 + l31;
            float bv = bias[o];
#pragma unroll
            for (int fm = 0; fm < 2; ++fm) {
#pragma unroll
                for (int r = 0; r < 16; ++r) {
                    float v = acc[fm][fn][r] + s_[(fm * 2 + fn) * 16 + r] + bv;
                    int token = m0 + fm * 32 + (r & 3) + 8 * (r >> 2) + 4 * half;
                    out[(size_t)token * OUT_FEAT + o] = v;
                }
            }
        }
    }
}

extern "C" void kernel_launch(void* const* d_in, const int* in_sizes, int n_in,
                              void* d_out, int out_size, void* d_ws, size_t ws_size,
                              hipStream_t stream) {
    const float* x            = (const float*)d_in[0];
    const float* coeff        = (const float*)d_in[1];
    const float* scale_base   = (const float*)d_in[2];
    const float* scale_spline = (const float*)d_in[3];
    const float* base_bias    = (const float*)d_in[4];
    float* out = (float*)d_out;

    short* Wb   = (short*)d_ws;                                  // 4 MB
    float* bias = (float*)((char*)d_ws + (size_t)OUT_FEAT * KDIM * 2);

    kan_prep<<<OUT_FEAT, 256, 0, stream>>>(coeff, scale_base, scale_spline, base_bias, Wb, bias);
    kan_gemm14<<<(NTOK / 64) * (OUT_FEAT / 64), 256, 0, stream>>>(x, Wb, bias, out);
}

// Round 6
// 135.892 us; speedup vs baseline: 1.0792x; 1.0792x over previous
//
#include <hip/hip_runtime.h>
#include <hip/hip_bf16.h>

// KAN linear == GEMM M=8192, N=512, K=4096 (8 Chebyshev/silu feats per input,
// basis_0 folded into bias). Round 15: R14's counted-vmcnt pipeline failed
// because the prefetch was 1-deep (wait < DMA latency) and sched_barrier(0)
// walls defeated compiler scheduling (m141). R15: triple-buffered Bs (48 KB),
// TWO-iteration-deep prefetch (iter k issues B(k+2)/x(k+2)), exactly one
// s_waitcnt vmcnt(6) per iter (never 0 in-loop, T4), raw s_barrier, NO
// sched_barriers. x stays in a 3-deep register ring (2 float4/iter). Gen
// packing via v_cvt_pk_bf16_f32 (gfx950, 1 inst/pair vs 3). Math verbatim
// from R13/R14 (both numerically verified): B XOR swizzle, frag offsets,
// 4-way split-K epilogue.
#define IN_FEAT 512
#define OUT_FEAT 512
#define NTOK 8192
#define KDIM 4096

typedef short bf16x8 __attribute__((ext_vector_type(8)));
typedef float f32x16 __attribute__((ext_vector_type(16)));

static __device__ inline short f2bf(float f) {
    union { float f; unsigned u; } v; v.f = f;
    unsigned u = v.u;
    u += 0x7fffu + ((u >> 16) & 1u);   // RNE
    return (short)(u >> 16);
}

static __device__ inline unsigned cvtpk(float lo, float hi) {
    unsigned r;
    asm("v_cvt_pk_bf16_f32 %0, %1, %2" : "=v"(r) : "v"(lo), "v"(hi));
    return r;
}

// 8 basis features of one (token,input): [silu(xc), xc, T2..T7]
static __device__ inline bf16x8 gen_chunk(float xv) {
    float xc = fminf(fmaxf(xv, -1.f), 1.f);
    float e  = __expf(-xc);
    float bse = xc * __builtin_amdgcn_rcpf(1.f + e);
    float b2 = 2.f * xc * xc - 1.f;
    float b3 = 2.f * xc * b2 - 1.f;
    float b4 = 2.f * xc * b3 - 1.f;
    float b5 = 2.f * xc * b4 - 1.f;
    float b6 = 2.f * xc * b5 - 1.f;
    float b7 = 2.f * xc * b6 - 1.f;
    union { uint4 u; bf16x8 v; } r;
    r.u.x = cvtpk(bse, xc);
    r.u.y = cvtpk(b2, b3);
    r.u.z = cvtpk(b4, b5);
    r.u.w = cvtpk(b6, b7);
    return r.v;
}

static __device__ inline void gload_lds16(const short* g, short* l) {
    __builtin_amdgcn_global_load_lds(
        (const __attribute__((address_space(1))) unsigned int*)g,
        (__attribute__((address_space(3))) unsigned int*)l,
        16, 0, 0);
}

// ---------------- prep: W bf16 [512 x 4096] + folded bias ----------------
__global__ __launch_bounds__(256) void kan_prep(
    const float* __restrict__ coeff, const float* __restrict__ scale_base,
    const float* __restrict__ scale_spline, const float* __restrict__ base_bias,
    short* __restrict__ Wb, float* __restrict__ bias)
{
    int o = blockIdx.x;
    int tid = threadIdx.x;
    float local = 0.f;
#pragma unroll
    for (int rep = 0; rep < 2; ++rep) {
        int i = tid + rep * 256;
        size_t oi = (size_t)o * IN_FEAT + i;
        const float4* c4 = (const float4*)(coeff + oi * 8);
        float4 ca = c4[0], cb = c4[1];
        float ss = scale_spline[oi];
        float sb = scale_base[oi];
        local += base_bias[oi] + ss * ca.x;
        bf16x8 w;
        w[0] = f2bf(sb);
        w[1] = f2bf(ss * ca.y); w[2] = f2bf(ss * ca.z); w[3] = f2bf(ss * ca.w);
        w[4] = f2bf(ss * cb.x); w[5] = f2bf(ss * cb.y); w[6] = f2bf(ss * cb.z);
        w[7] = f2bf(ss * cb.w);
        *(bf16x8*)(Wb + (size_t)o * KDIM + (size_t)i * 8) = w;
    }
    __shared__ float red[4];
    for (int off = 32; off > 0; off >>= 1) local += __shfl_down(local, off, 64);
    int lane = tid & 63, wv = tid >> 6;
    if (lane == 0) red[wv] = local;
    __syncthreads();
    if (tid == 0) bias[o] = red[0] + red[1] + red[2] + red[3];
}

// --- 32x32x16 fused GEMM, 64m x 64n, 4-way split-K, 3-buf 2-deep pipeline ---
__global__ __launch_bounds__(256, 3) void kan_gemm15(
    const float* __restrict__ x, const short* __restrict__ Wb,
    const float* __restrict__ bias, float* __restrict__ out)
{
    // LDS 49152 B: Bs triple-buffer [3][64 rows][16 slots][8 shorts]
    // (phys slot = clog ^ (row&15), verbatim R13). Epilogue rbuf overlays.
    __shared__ __align__(16) short POOL[24576];
    short* Bs = POOL;                     // [3][8192]

    int tid = threadIdx.x;
    int nb = blockIdx.x & 7;         // XCD j sees nb=j -> 0.5 MB W slice per XCD L2
    int mb = blockIdx.x >> 3;        // 128 m-tiles
    int m0 = mb * 64, o0 = nb * 64;

    int lane = tid & 63, wv = tid >> 6;
    int kk = wv;                     // wave = 64m x 64n on K-quarter kk
    int l31 = lane & 31, half = lane >> 5;
    int rm  = l31 & 15;

    f32x16 acc[2][2];                // [fm][fn], 32x32 each
#pragma unroll
    for (int a = 0; a < 2; ++a)
#pragma unroll
        for (int b = 0; b < 2; ++b) acc[a][b] = (f32x16)0.f;

    // B DMA pointers (verbatim R13): wave wv stages rows [wv*16,+16), 4 calls.
    int rl = lane >> 4, q = lane & 15;
    const short* pB0 = Wb + (size_t)(o0 + wv * 16 +  0 + rl) * KDIM + (size_t)(q ^ ( 0 + rl)) * 8;
    const short* pB1 = Wb + (size_t)(o0 + wv * 16 +  4 + rl) * KDIM + (size_t)(q ^ ( 4 + rl)) * 8;
    const short* pB2 = Wb + (size_t)(o0 + wv * 16 +  8 + rl) * KDIM + (size_t)(q ^ ( 8 + rl)) * 8;
    const short* pB3 = Wb + (size_t)(o0 + wv * 16 + 12 + rl) * KDIM + (size_t)(q ^ (12 + rl)) * 8;

    // x: wave kk consumes cols [kk*4, kk*4+4) of each 16-col K-block -> one
    // aligned float4 per token-group per iter, straight to registers.
    const float* xp0 = x + (size_t)(m0 + l31) * IN_FEAT + kk * 4;

    // Constant frag-read offsets (shorts): col s0 = kk*4+half, s1 = s0+2.
    int s0 = kk * 4 + half, s1 = s0 + 2;
    int of00 = l31 * 128        + ((s0 ^ rm) * 8);
    int of01 = (32 + l31) * 128 + ((s0 ^ rm) * 8);
    int of10 = l31 * 128        + ((s1 ^ rm) * 8);
    int of11 = (32 + l31) * 128 + ((s1 ^ rm) * 8);

#define COMPUTE(CUR, P0, P1)                                                  \
    {                                                                         \
        const short* Bsc_ = Bs + (CUR) * 8192;                                \
        bf16x8 b00 = *(const bf16x8*)(Bsc_ + of00);                           \
        bf16x8 b01 = *(const bf16x8*)(Bsc_ + of01);                           \
        bf16x8 b10 = *(const bf16x8*)(Bsc_ + of10);                           \
        bf16x8 b11 = *(const bf16x8*)(Bsc_ + of11);                           \
        bf16x8 a00 = gen_chunk(half ? (P0).y : (P0).x);                       \
        bf16x8 a01 = gen_chunk(half ? (P1).y : (P1).x);                       \
        bf16x8 a10 = gen_chunk(half ? (P0).w : (P0).z);                       \
        bf16x8 a11 = gen_chunk(half ? (P1).w : (P1).z);                       \
        __builtin_amdgcn_s_setprio(1);                                        \
        acc[0][0] = __builtin_amdgcn_mfma_f32_32x32x16_bf16(a00, b00, acc[0][0], 0, 0, 0); \
        acc[0][1] = __builtin_amdgcn_mfma_f32_32x32x16_bf16(a00, b01, acc[0][1], 0, 0, 0); \
        acc[1][0] = __builtin_amdgcn_mfma_f32_32x32x16_bf16(a01, b00, acc[1][0], 0, 0, 0); \
        acc[1][1] = __builtin_amdgcn_mfma_f32_32x32x16_bf16(a01, b01, acc[1][1], 0, 0, 0); \
        acc[0][0] = __builtin_amdgcn_mfma_f32_32x32x16_bf16(a10, b10, acc[0][0], 0, 0, 0); \
        acc[0][1] = __builtin_amdgcn_mfma_f32_32x32x16_bf16(a10, b11, acc[0][1], 0, 0, 0); \
        acc[1][0] = __builtin_amdgcn_mfma_f32_32x32x16_bf16(a11, b10, acc[1][0], 0, 0, 0); \
        acc[1][1] = __builtin_amdgcn_mfma_f32_32x32x16_bf16(a11, b11, acc[1][1], 0, 0, 0); \
        __builtin_amdgcn_s_setprio(0);                                        \
    }

#define ISSUE_B(DST, IT)                                                      \
    {                                                                         \
        short* bd_ = Bs + (DST) * 8192 + wv * 2048;                           \
        const size_t bo_ = (size_t)(IT) * 128;                                \
        gload_lds16(pB0 + bo_, bd_);                                          \
        gload_lds16(pB1 + bo_, bd_ + 512);                                    \
        gload_lds16(pB2 + bo_, bd_ + 1024);                                   \
        gload_lds16(pB3 + bo_, bd_ + 1536);                                   \
    }

    // Steady-state invariant at ITER(k) entry (post-barrier): outstanding
    // vmem = B(k+1)[4] + x(k+1)[2] = 6, B(k) in LDS, x(k) in pend regs.
    // ITER(k): issue B(k+2)+x(k+2) (-> 12 outstanding), compute(k),
    // vmcnt(6) drains B(k+1)+x(k+1), barrier. vmcnt never 0 in-loop.
#define ITER(IT, CUR, DST, PC0, PC1, PN0, PN1)                                \
    {                                                                         \
        ISSUE_B(DST, (IT) + 2);                                               \
        {                                                                     \
            const float* xq_ = xp0 + (size_t)((IT) + 2) * 16;                 \
            PN0 = *(const float4*)(xq_);                                      \
            PN1 = *(const float4*)(xq_ + 16384);                              \
        }                                                                     \
        COMPUTE(CUR, PC0, PC1);                                               \
        asm volatile("s_waitcnt vmcnt(6)" ::: "memory");                      \
        __builtin_amdgcn_s_barrier();                                         \
    }

    float4 Pa0, Pa1, Pb0, Pb1, Pc0, Pc1;

    // ---- prologue: issue B(0),x(0),B(1),x(1); drain B(0)+x(0); publish ----
    ISSUE_B(0, 0);
    Pa0 = *(const float4*)(xp0);
    Pa1 = *(const float4*)(xp0 + 16384);
    ISSUE_B(1, 1);
    Pb0 = *(const float4*)(xp0 + 16);
    Pb1 = *(const float4*)(xp0 + 16 + 16384);
    asm volatile("s_waitcnt vmcnt(6)" ::: "memory");
    __builtin_amdgcn_s_barrier();

    // ---- main: iters 0..29, buf = k%3, pend set = k%3 ----
    for (int j = 0; j < 10; ++j) {
        ITER(3 * j,     0, 2, Pa0, Pa1, Pc0, Pc1);
        ITER(3 * j + 1, 1, 0, Pb0, Pb1, Pa0, Pa1);
        ITER(3 * j + 2, 2, 1, Pc0, Pc1, Pb0, Pb1);
    }

    // ---- tail: iter 30 (buf0, consume Pa; drain everything), iter 31 ----
    COMPUTE(0, Pa0, Pa1);
    asm volatile("s_waitcnt vmcnt(0)" ::: "memory");
    __builtin_amdgcn_s_barrier();
    COMPUTE(1, Pb0, Pb1);
#undef ITER
#undef ISSUE_B
#undef COMPUTE

    // ---- epilogue: 4-way split-K reduce through LDS (verbatim R13) ----
    float* rbuf = (float*)POOL;      // 12288 floats; max used 4224+4221 = 8445
    __syncthreads();                 // everyone done with Bs
    if (kk >= 2) {                   // kk=2 -> slab 0, kk=3 -> slab 1
        float* s_ = rbuf + (size_t)(kk - 2) * 4224 + lane * 66;
#pragma unroll
        for (int fm = 0; fm < 2; ++fm)
#pragma unroll
            for (int fn = 0; fn < 2; ++fn)
#pragma unroll
                for (int r = 0; r < 16; ++r)
                    s_[(fm * 2 + fn) * 16 + r] = acc[fm][fn][r];
    }
    __syncthreads();
    if (kk < 2) {                    // kk0 += kk2, kk1 += kk3
        const float* s_ = rbuf + (size_t)kk * 4224 + lane * 66;
#pragma unroll
        for (int fm = 0; fm < 2; ++fm)
#pragma unroll
            for (int fn = 0; fn < 2; ++fn)
#pragma unroll
                for (int r = 0; r < 16; ++r)
                    acc[fm][fn][r] += s_[(fm * 2 + fn) * 16 + r];
    }
    __syncthreads();
    if (kk == 1) {                   // kk1 partial -> slab 0
        float* s_ = rbuf + lane * 66;
#pragma unroll
        for (int fm = 0; fm < 2; ++fm)
#pragma unroll
            for (int fn = 0; fn < 2; ++fn)
#pragma unroll
                for (int r = 0; r < 16; ++r)
                    s_[(fm * 2 + fn) * 16 + r] = acc[fm][fn][r];
    }
    __syncthreads();
    if (kk == 0) {
        const float* s_ = rbuf + lane * 66;
        // C/D layout (32x32): col = lane&31, row = (r&3) + 8*(r>>2) + 4*(lane>>5)
#pragma unroll
        for (int fn = 0; fn < 2; ++fn) {
            int o = o0 + fn * 32 + l31;
            float bv = bias[o];
#pragma unroll
            for (int fm = 0; fm < 2; ++fm) {
#pragma unroll
                for (int r = 0; r < 16; ++r) {
                    float v = acc[fm][fn][r] + s_[(fm * 2 + fn) * 16 + r] + bv;
                    int token = m0 + fm * 32 + (r & 3) + 8 * (r >> 2) + 4 * half;
                    out[(size_t)token * OUT_FEAT + o] = v;
                }
            }
        }
    }
}

extern "C" void kernel_launch(void* const* d_in, const int* in_sizes, int n_in,
                              void* d_out, int out_size, void* d_ws, size_t ws_size,
                              hipStream_t stream) {
    const float* x            = (const float*)d_in[0];
    const float* coeff        = (const float*)d_in[1];
    const float* scale_base   = (const float*)d_in[2];
    const float* scale_spline = (const float*)d_in[3];
    const float* base_bias    = (const float*)d_in[4];
    float* out = (float*)d_out;

    short* Wb   = (short*)d_ws;                                  // 4 MB
    float* bias = (float*)((char*)d_ws + (size_t)OUT_FEAT * KDIM * 2);

    kan_prep<<<OUT_FEAT, 256, 0, stream>>>(coeff, scale_base, scale_spline, base_bias, Wb, bias);
    kan_gemm15<<<(NTOK / 64) * (OUT_FEAT / 64), 256, 0, stream>>>(x, Wb, bias, out);
}

// Round 7
// 127.885 us; speedup vs baseline: 1.1468x; 1.0626x over previous
//
#include <hip/hip_runtime.h>
#include <hip/hip_bf16.h>

// KAN linear == GEMM M=8192, N=512, K=4096 (8 Chebyshev/silu feats per input,
// basis_0 folded into bias). Round 16: R9-R15 all land at ~66us with every
// pipe <40% busy; per-iter wall fits t = 0.45us fixed + bytes-staged term.
// Both surviving theories (L2->CU return BW on W; fixed per-iter latency)
// have the same fix: more MFMA per staged byte. R16 doubles the M-tile:
// 128m x 64n blocks (grid 512, 2 blk/CU), acc[4][2], 16 MFMA / 8 gen per
// iter against the SAME 4 B-frags -> W reuse 2x, per-CU staged bytes 4->1.5
// MB. x in registers (R14/15-verified scheme, 4 aligned float4/lane/iter).
// Everything else verbatim R13 (verified): B DMA + XOR-16 swizzle, frag
// offsets, 2-phase sync, 4-way split-K epilogue (run twice, fm-pairs).
#define IN_FEAT 512
#define OUT_FEAT 512
#define NTOK 8192
#define KDIM 4096

typedef short bf16x8 __attribute__((ext_vector_type(8)));
typedef float f32x16 __attribute__((ext_vector_type(16)));

static __device__ inline short f2bf(float f) {
    union { float f; unsigned u; } v; v.f = f;
    unsigned u = v.u;
    u += 0x7fffu + ((u >> 16) & 1u);   // RNE
    return (short)(u >> 16);
}

static __device__ inline unsigned cvtpk(float lo, float hi) {
    unsigned r;
    asm("v_cvt_pk_bf16_f32 %0, %1, %2" : "=v"(r) : "v"(lo), "v"(hi));
    return r;
}

// 8 basis features of one (token,input): [silu(xc), xc, T2..T7]
static __device__ inline bf16x8 gen_chunk(float xv) {
    float xc = fminf(fmaxf(xv, -1.f), 1.f);
    float e  = __expf(-xc);
    float bse = xc * __builtin_amdgcn_rcpf(1.f + e);
    float b2 = 2.f * xc * xc - 1.f;
    float b3 = 2.f * xc * b2 - 1.f;
    float b4 = 2.f * xc * b3 - 1.f;
    float b5 = 2.f * xc * b4 - 1.f;
    float b6 = 2.f * xc * b5 - 1.f;
    float b7 = 2.f * xc * b6 - 1.f;
    union { uint4 u; bf16x8 v; } r;
    r.u.x = cvtpk(bse, xc);
    r.u.y = cvtpk(b2, b3);
    r.u.z = cvtpk(b4, b5);
    r.u.w = cvtpk(b6, b7);
    return r.v;
}

static __device__ inline void gload_lds16(const short* g, short* l) {
    __builtin_amdgcn_global_load_lds(
        (const __attribute__((address_space(1))) unsigned int*)g,
        (__attribute__((address_space(3))) unsigned int*)l,
        16, 0, 0);
}

// ---------------- prep: W bf16 [512 x 4096] + folded bias ----------------
__global__ __launch_bounds__(256) void kan_prep(
    const float* __restrict__ coeff, const float* __restrict__ scale_base,
    const float* __restrict__ scale_spline, const float* __restrict__ base_bias,
    short* __restrict__ Wb, float* __restrict__ bias)
{
    int o = blockIdx.x;
    int tid = threadIdx.x;
    float local = 0.f;
#pragma unroll
    for (int rep = 0; rep < 2; ++rep) {
        int i = tid + rep * 256;
        size_t oi = (size_t)o * IN_FEAT + i;
        const float4* c4 = (const float4*)(coeff + oi * 8);
        float4 ca = c4[0], cb = c4[1];
        float ss = scale_spline[oi];
        float sb = scale_base[oi];
        local += base_bias[oi] + ss * ca.x;
        bf16x8 w;
        w[0] = f2bf(sb);
        w[1] = f2bf(ss * ca.y); w[2] = f2bf(ss * ca.z); w[3] = f2bf(ss * ca.w);
        w[4] = f2bf(ss * cb.x); w[5] = f2bf(ss * cb.y); w[6] = f2bf(ss * cb.z);
        w[7] = f2bf(ss * cb.w);
        *(bf16x8*)(Wb + (size_t)o * KDIM + (size_t)i * 8) = w;
    }
    __shared__ float red[4];
    for (int off = 32; off > 0; off >>= 1) local += __shfl_down(local, off, 64);
    int lane = tid & 63, wv = tid >> 6;
    if (lane == 0) red[wv] = local;
    __syncthreads();
    if (tid == 0) bias[o] = red[0] + red[1] + red[2] + red[3];
}

// -- 32x32x16 fused GEMM, 128m x 64n blocks, 4-way split-K waves, 40 KB LDS --
__global__ __launch_bounds__(256, 2) void kan_gemm16(
    const float* __restrict__ x, const short* __restrict__ Wb,
    const float* __restrict__ bias, float* __restrict__ out)
{
    // LDS pool, 40960 B: Bs dbuf [2][64 rows][16 slots][8 shorts] = 32 KB
    // (phys slot = clog ^ (row&15), verbatim R13); epilogue rbuf overlays.
    __shared__ __align__(16) short POOL[20480];
    short* Bs = POOL;                     // [2][8192]

    int tid = threadIdx.x;
    int nb = blockIdx.x & 7;         // XCD j sees nb=j -> 0.5 MB W slice per XCD L2
    int mb = blockIdx.x >> 3;        // 64 m-tiles
    int m0 = mb * 128, o0 = nb * 64;

    int lane = tid & 63, wv = tid >> 6;
    int kk = wv;                     // wave = 128m x 64n on K-quarter kk
    int l31 = lane & 31, half = lane >> 5;
    int rm  = l31 & 15;

    f32x16 acc[4][2];                // [FM token-group][fn], 32x32 each
#pragma unroll
    for (int a = 0; a < 4; ++a)
#pragma unroll
        for (int b = 0; b < 2; ++b) acc[a][b] = (f32x16)0.f;

    // B DMA pointers (verbatim R13): wave wv stages rows [wv*16,+16), 4 calls.
    int rl = lane >> 4, q = lane & 15;
    const short* pB0 = Wb + (size_t)(o0 + wv * 16 +  0 + rl) * KDIM + (size_t)(q ^ ( 0 + rl)) * 8;
    const short* pB1 = Wb + (size_t)(o0 + wv * 16 +  4 + rl) * KDIM + (size_t)(q ^ ( 4 + rl)) * 8;
    const short* pB2 = Wb + (size_t)(o0 + wv * 16 +  8 + rl) * KDIM + (size_t)(q ^ ( 8 + rl)) * 8;
    const short* pB3 = Wb + (size_t)(o0 + wv * 16 + 12 + rl) * KDIM + (size_t)(q ^ (12 + rl)) * 8;

    // x: wave kk consumes cols [kk*4, kk*4+4) of each 16-col K-block; four
    // token groups (m0 + l31 + {0,32,64,96}) -> 4 aligned float4 per iter,
    // straight to registers (R14/R15-verified scheme).
    const float* xp0 = x + (size_t)(m0 + l31) * IN_FEAT + kk * 4;

    // Constant frag-read offsets (shorts): col s0 = kk*4+half, s1 = s0+2.
    int s0 = kk * 4 + half, s1 = s0 + 2;
    int of00 = l31 * 128        + ((s0 ^ rm) * 8);
    int of01 = (32 + l31) * 128 + ((s0 ^ rm) * 8);
    int of10 = l31 * 128        + ((s1 ^ rm) * 8);
    int of11 = (32 + l31) * 128 + ((s1 ^ rm) * 8);

#define MFMA_(A, B, C) __builtin_amdgcn_mfma_f32_32x32x16_bf16(A, B, C, 0, 0, 0)

#define STAGE(BUF, IT, P0, P1, P2, P3)                                        \
    {                                                                         \
        short* bd_ = Bs + (BUF) * 8192 + wv * 2048;                           \
        const size_t bo_ = (size_t)(IT) * 128;                                \
        gload_lds16(pB0 + bo_, bd_);                                          \
        gload_lds16(pB1 + bo_, bd_ + 512);                                    \
        gload_lds16(pB2 + bo_, bd_ + 1024);                                   \
        gload_lds16(pB3 + bo_, bd_ + 1536);                                   \
        const float* xq_ = xp0 + (size_t)(IT) * 16;                           \
        P0 = *(const float4*)(xq_);                                           \
        P1 = *(const float4*)(xq_ + 16384);                                   \
        P2 = *(const float4*)(xq_ + 32768);                                   \
        P3 = *(const float4*)(xq_ + 49152);                                   \
    }

#define COMPUTE(CUR, P0, P1, P2, P3)                                          \
    {                                                                         \
        const short* Bsc_ = Bs + (CUR) * 8192;                                \
        bf16x8 b00 = *(const bf16x8*)(Bsc_ + of00);                           \
        bf16x8 b01 = *(const bf16x8*)(Bsc_ + of01);                           \
        bf16x8 b10 = *(const bf16x8*)(Bsc_ + of10);                           \
        bf16x8 b11 = *(const bf16x8*)(Bsc_ + of11);                           \
        bf16x8 a0 = gen_chunk(half ? (P0).y : (P0).x);                        \
        bf16x8 a1 = gen_chunk(half ? (P1).y : (P1).x);                        \
        bf16x8 a2 = gen_chunk(half ? (P2).y : (P2).x);                        \
        bf16x8 a3 = gen_chunk(half ? (P3).y : (P3).x);                        \
        acc[0][0] = MFMA_(a0, b00, acc[0][0]); acc[0][1] = MFMA_(a0, b01, acc[0][1]); \
        acc[1][0] = MFMA_(a1, b00, acc[1][0]); acc[1][1] = MFMA_(a1, b01, acc[1][1]); \
        acc[2][0] = MFMA_(a2, b00, acc[2][0]); acc[2][1] = MFMA_(a2, b01, acc[2][1]); \
        acc[3][0] = MFMA_(a3, b00, acc[3][0]); acc[3][1] = MFMA_(a3, b01, acc[3][1]); \
        a0 = gen_chunk(half ? (P0).w : (P0).z);                               \
        a1 = gen_chunk(half ? (P1).w : (P1).z);                               \
        a2 = gen_chunk(half ? (P2).w : (P2).z);                               \
        a3 = gen_chunk(half ? (P3).w : (P3).z);                               \
        acc[0][0] = MFMA_(a0, b10, acc[0][0]); acc[0][1] = MFMA_(a0, b11, acc[0][1]); \
        acc[1][0] = MFMA_(a1, b10, acc[1][0]); acc[1][1] = MFMA_(a1, b11, acc[1][1]); \
        acc[2][0] = MFMA_(a2, b10, acc[2][0]); acc[2][1] = MFMA_(a2, b11, acc[2][1]); \
        acc[3][0] = MFMA_(a3, b10, acc[3][0]); acc[3][1] = MFMA_(a3, b11, acc[3][1]); \
    }

    float4 Pa0, Pa1, Pa2, Pa3, Pb0, Pb1, Pb2, Pb3;

    // R13 2-phase schedule: stage(0) before loop; each iter: barrier
    // (syncthreads drains DMA + x-loads), stage(it+1), compute(it).
    STAGE(0, 0, Pa0, Pa1, Pa2, Pa3);
    for (int j = 0; j < 16; ++j) {
        const int e = 2 * j;         // even iter: consume A/buf0, stage B/buf1
        __syncthreads();
        STAGE(1, e + 1, Pb0, Pb1, Pb2, Pb3);          // e+1 <= 31 always
        COMPUTE(0, Pa0, Pa1, Pa2, Pa3);
        __syncthreads();
        if (e + 1 < 31) STAGE(0, e + 2, Pa0, Pa1, Pa2, Pa3);
        COMPUTE(1, Pb0, Pb1, Pb2, Pb3);
    }
#undef STAGE
#undef COMPUTE
#undef MFMA_

    // ---- epilogue: 4-way split-K reduce (verbatim R13), two fm-pair passes ----
    float* rbuf = (float*)POOL;      // 10240 floats; max used 4224+4221 = 8445
#pragma unroll
    for (int p = 0; p < 2; ++p) {
        __syncthreads();             // pass 0: everyone done with Bs; pass 1: prev done
        if (kk >= 2) {               // kk=2 -> slab 0, kk=3 -> slab 1
            float* s_ = rbuf + (size_t)(kk - 2) * 4224 + lane * 66;
#pragma unroll
            for (int fm = 0; fm < 2; ++fm)
#pragma unroll
                for (int fn = 0; fn < 2; ++fn)
#pragma unroll
                    for (int r = 0; r < 16; ++r)
                        s_[(fm * 2 + fn) * 16 + r] = acc[2 * p + fm][fn][r];
        }
        __syncthreads();
        if (kk < 2) {                // kk0 += kk2, kk1 += kk3
            const float* s_ = rbuf + (size_t)kk * 4224 + lane * 66;
#pragma unroll
            for (int fm = 0; fm < 2; ++fm)
#pragma unroll
                for (int fn = 0; fn < 2; ++fn)
#pragma unroll
                    for (int r = 0; r < 16; ++r)
                        acc[2 * p + fm][fn][r] += s_[(fm * 2 + fn) * 16 + r];
        }
        __syncthreads();
        if (kk == 1) {               // kk1 partial -> slab 0
            float* s_ = rbuf + lane * 66;
#pragma unroll
            for (int fm = 0; fm < 2; ++fm)
#pragma unroll
                for (int fn = 0; fn < 2; ++fn)
#pragma unroll
                    for (int r = 0; r < 16; ++r)
                        s_[(fm * 2 + fn) * 16 + r] = acc[2 * p + fm][fn][r];
        }
        __syncthreads();
        if (kk == 0) {
            const float* s_ = rbuf + lane * 66;
            // C/D layout (32x32): col = lane&31, row = (r&3)+8*(r>>2)+4*(lane>>5)
#pragma unroll
            for (int fn = 0; fn < 2; ++fn) {
                int o = o0 + fn * 32 + l31;
                float bv = bias[o];
#pragma unroll
                for (int fm = 0; fm < 2; ++fm) {
#pragma unroll
                    for (int r = 0; r < 16; ++r) {
                        float v = acc[2 * p + fm][fn][r] + s_[(fm * 2 + fn) * 16 + r] + bv;
                        int token = m0 + (2 * p + fm) * 32 + (r & 3) + 8 * (r >> 2) + 4 * half;
                        out[(size_t)token * OUT_FEAT + o] = v;
                    }
                }
            }
        }
    }
}

extern "C" void kernel_launch(void* const* d_in, const int* in_sizes, int n_in,
                              void* d_out, int out_size, void* d_ws, size_t ws_size,
                              hipStream_t stream) {
    const float* x            = (const float*)d_in[0];
    const float* coeff        = (const float*)d_in[1];
    const float* scale_base   = (const float*)d_in[2];
    const float* scale_spline = (const float*)d_in[3];
    const float* base_bias    = (const float*)d_in[4];
    float* out = (float*)d_out;

    short* Wb   = (short*)d_ws;                                  // 4 MB
    float* bias = (float*)((char*)d_ws + (size_t)OUT_FEAT * KDIM * 2);

    kan_prep<<<OUT_FEAT, 256, 0, stream>>>(coeff, scale_base, scale_spline, base_bias, Wb, bias);
    kan_gemm16<<<(NTOK / 128) * (OUT_FEAT / 64), 256, 0, stream>>>(x, Wb, bias, out);
}

// Round 8
// 126.477 us; speedup vs baseline: 1.1595x; 1.0111x over previous
//
#include <hip/hip_runtime.h>
#include <hip/hip_bf16.h>

// KAN linear == GEMM M=8192, N=512, K=4096 (8 Chebyshev/silu feats per input,
// basis_0 folded into bias). Round 17: the cross-round invariant is
// fetch-bound latency: FETCH_SIZE/achieved-rate = 46-51us in R9/R13/R16 ==
// the measured work-term. Two levers, math otherwise verbatim R16 (verified):
//  1) XCD x-locality: all 8 nb-blocks of an mb on ONE XCD (mb=(bid&7)*8+(t&7),
//     nb=t>>3) -> per-XCD x-slice 2 MB (L2-fits), x HBM-fetched once.
//     Predicted FETCH 67.6 -> ~24 MB.
//  2) K-step 256 (16 iters, halves the ~1us/iter fixed barrier/latency cost;
//     R11<->R13 measured 0.45-1us/iter). Bs dbuf [2][64 rows][32 slots][8]
//     = 64 KB, phys slot = g ^ (row&31) (R13's verified involution, mod-32).
// x stays in registers: 8 aligned float4/lane/iter (2 per token-group).
#define IN_FEAT 512
#define OUT_FEAT 512
#define NTOK 8192
#define KDIM 4096

typedef short bf16x8 __attribute__((ext_vector_type(8)));
typedef float f32x16 __attribute__((ext_vector_type(16)));

static __device__ inline short f2bf(float f) {
    union { float f; unsigned u; } v; v.f = f;
    unsigned u = v.u;
    u += 0x7fffu + ((u >> 16) & 1u);   // RNE
    return (short)(u >> 16);
}

static __device__ inline unsigned cvtpk(float lo, float hi) {
    unsigned r;
    asm("v_cvt_pk_bf16_f32 %0, %1, %2" : "=v"(r) : "v"(lo), "v"(hi));
    return r;
}

// 8 basis features of one (token,input): [silu(xc), xc, T2..T7]
static __device__ inline bf16x8 gen_chunk(float xv) {
    float xc = fminf(fmaxf(xv, -1.f), 1.f);
    float e  = __expf(-xc);
    float bse = xc * __builtin_amdgcn_rcpf(1.f + e);
    float b2 = 2.f * xc * xc - 1.f;
    float b3 = 2.f * xc * b2 - 1.f;
    float b4 = 2.f * xc * b3 - 1.f;
    float b5 = 2.f * xc * b4 - 1.f;
    float b6 = 2.f * xc * b5 - 1.f;
    float b7 = 2.f * xc * b6 - 1.f;
    union { uint4 u; bf16x8 v; } r;
    r.u.x = cvtpk(bse, xc);
    r.u.y = cvtpk(b2, b3);
    r.u.z = cvtpk(b4, b5);
    r.u.w = cvtpk(b6, b7);
    return r.v;
}

static __device__ inline void gload_lds16(const short* g, short* l) {
    __builtin_amdgcn_global_load_lds(
        (const __attribute__((address_space(1))) unsigned int*)g,
        (__attribute__((address_space(3))) unsigned int*)l,
        16, 0, 0);
}

// ---------------- prep: W bf16 [512 x 4096] + folded bias ----------------
__global__ __launch_bounds__(256) void kan_prep(
    const float* __restrict__ coeff, const float* __restrict__ scale_base,
    const float* __restrict__ scale_spline, const float* __restrict__ base_bias,
    short* __restrict__ Wb, float* __restrict__ bias)
{
    int o = blockIdx.x;
    int tid = threadIdx.x;
    float local = 0.f;
#pragma unroll
    for (int rep = 0; rep < 2; ++rep) {
        int i = tid + rep * 256;
        size_t oi = (size_t)o * IN_FEAT + i;
        const float4* c4 = (const float4*)(coeff + oi * 8);
        float4 ca = c4[0], cb = c4[1];
        float ss = scale_spline[oi];
        float sb = scale_base[oi];
        local += base_bias[oi] + ss * ca.x;
        bf16x8 w;
        w[0] = f2bf(sb);
        w[1] = f2bf(ss * ca.y); w[2] = f2bf(ss * ca.z); w[3] = f2bf(ss * ca.w);
        w[4] = f2bf(ss * cb.x); w[5] = f2bf(ss * cb.y); w[6] = f2bf(ss * cb.z);
        w[7] = f2bf(ss * cb.w);
        *(bf16x8*)(Wb + (size_t)o * KDIM + (size_t)i * 8) = w;
    }
    __shared__ float red[4];
    for (int off = 32; off > 0; off >>= 1) local += __shfl_down(local, off, 64);
    int lane = tid & 63, wv = tid >> 6;
    if (lane == 0) red[wv] = local;
    __syncthreads();
    if (tid == 0) bias[o] = red[0] + red[1] + red[2] + red[3];
}

// 32x32x16 fused GEMM, 128m x 64n, 4-way split-K, K-step 256, XCD x-locality
__global__ __launch_bounds__(256, 2) void kan_gemm17(
    const float* __restrict__ x, const short* __restrict__ Wb,
    const float* __restrict__ bias, float* __restrict__ out)
{
    // LDS 65536 B: Bs dbuf [2][64 rows][32 slots][8 shorts]
    // (phys slot = g ^ (row&31)); epilogue rbuf overlays.
    __shared__ __align__(16) short POOL[32768];
    short* Bs = POOL;                     // [2][16384]

    int tid = threadIdx.x;
    int bid = blockIdx.x;
    // XCD j (= bid%8, HW round-robin) gets mb in [j*8, j*8+8) x all 8 nb:
    // x-slice 2 MB/XCD (L2-fits, HBM-fetched once); W full but slab-streamed.
    int j8 = bid & 7, t = bid >> 3;
    int mb = j8 * 8 + (t & 7);       // 64 m-tiles of 128 tokens
    int nb = t >> 3;                 // 8 n-tiles of 64 outs
    int m0 = mb * 128, o0 = nb * 64;

    int lane = tid & 63, wv = tid >> 6;
    int kk = wv;                     // wave = 128m x 64n on K-quarter kk
    int l31 = lane & 31, half = lane >> 5;

    f32x16 acc[4][2];                // [token-group][fn], 32x32 each
#pragma unroll
    for (int a = 0; a < 4; ++a)
#pragma unroll
        for (int b = 0; b < 2; ++b) acc[a][b] = (f32x16)0.f;

    // B DMA: wave wv stages rows [wv*16,+16) x 32 slots, 8 calls of 2 rows.
    // call c, lane i: row = wv*16 + c*2 + (i>>5), phys slot = i&31 holds
    // logical g = (i&31) ^ (row & 31); source pre-swizzled.
    int rl2 = lane >> 5, q32 = lane & 31;
    const short* pB[8];
#pragma unroll
    for (int c = 0; c < 8; ++c) {
        int row = wv * 16 + c * 2 + rl2;
        int g = q32 ^ (row & 31);
        pB[c] = Wb + (size_t)(o0 + row) * KDIM + (size_t)g * 8;
    }
    int bd0 = wv * 16 * 256;         // shorts offset of wave's rows in a buffer

    // x: wave kk consumes cols [kk*8, kk*8+8) of each 32-col K-block; four
    // token groups (m0 + g*32 + l31) -> 2 aligned float4 per group per iter.
    const float* xp0 = x + (size_t)(m0 + l31) * IN_FEAT + kk * 8;

    // Frag-read offsets (shorts): j=0..3, col s_j = kk*8 + 2j + half;
    // row fn*32+l31 -> row&31 == l31; fn=1 adds 32*256 = 8192.
    int ofr[4];
#pragma unroll
    for (int j = 0; j < 4; ++j)
        ofr[j] = l31 * 256 + (((kk * 8 + 2 * j + half) ^ l31) * 8);

#define MFMA_(A, B, C) __builtin_amdgcn_mfma_f32_32x32x16_bf16(A, B, C, 0, 0, 0)

#define GENSEL(Qa, Qb, J) ((J) == 0 ? (half ? (Qa).y : (Qa).x)                \
                         : (J) == 1 ? (half ? (Qa).w : (Qa).z)                \
                         : (J) == 2 ? (half ? (Qb).y : (Qb).x)                \
                                    : (half ? (Qb).w : (Qb).z))

#define STAGE(BUF, IT, Q0a, Q0b, Q1a, Q1b, Q2a, Q2b, Q3a, Q3b)                \
    {                                                                         \
        short* bd_ = Bs + (BUF) * 16384 + bd0;                                \
        const size_t bo_ = (size_t)(IT) * 256;                                \
        _Pragma("unroll")                                                     \
        for (int c_ = 0; c_ < 8; ++c_)                                        \
            gload_lds16(pB[c_] + bo_, bd_ + c_ * 512);                        \
        const float* xq_ = xp0 + (size_t)(IT) * 32;                           \
        Q0a = *(const float4*)(xq_);          Q0b = *(const float4*)(xq_ + 4);          \
        Q1a = *(const float4*)(xq_ + 16384);  Q1b = *(const float4*)(xq_ + 16388);      \
        Q2a = *(const float4*)(xq_ + 32768);  Q2b = *(const float4*)(xq_ + 32772);      \
        Q3a = *(const float4*)(xq_ + 49152);  Q3b = *(const float4*)(xq_ + 49156);      \
    }

#define COMPUTE(CUR, Q0a, Q0b, Q1a, Q1b, Q2a, Q2b, Q3a, Q3b)                  \
    {                                                                         \
        const short* Bc_ = Bs + (CUR) * 16384;                                \
        _Pragma("unroll")                                                     \
        for (int j_ = 0; j_ < 4; ++j_) {                                      \
            bf16x8 b0_ = *(const bf16x8*)(Bc_ + ofr[j_]);                     \
            bf16x8 b1_ = *(const bf16x8*)(Bc_ + ofr[j_] + 8192);              \
            bf16x8 a0_ = gen_chunk(GENSEL(Q0a, Q0b, j_));                     \
            bf16x8 a1_ = gen_chunk(GENSEL(Q1a, Q1b, j_));                     \
            bf16x8 a2_ = gen_chunk(GENSEL(Q2a, Q2b, j_));                     \
            bf16x8 a3_ = gen_chunk(GENSEL(Q3a, Q3b, j_));                     \
            acc[0][0] = MFMA_(a0_, b0_, acc[0][0]); acc[0][1] = MFMA_(a0_, b1_, acc[0][1]); \
            acc[1][0] = MFMA_(a1_, b0_, acc[1][0]); acc[1][1] = MFMA_(a1_, b1_, acc[1][1]); \
            acc[2][0] = MFMA_(a2_, b0_, acc[2][0]); acc[2][1] = MFMA_(a2_, b1_, acc[2][1]); \
            acc[3][0] = MFMA_(a3_, b0_, acc[3][0]); acc[3][1] = MFMA_(a3_, b1_, acc[3][1]); \
        }                                                                     \
    }

    float4 A0a, A0b, A1a, A1b, A2a, A2b, A3a, A3b;
    float4 B0a, B0b, B1a, B1b, B2a, B2b, B3a, B3b;

    // R13/R16 2-phase schedule: stage(0); each iter: barrier (drains DMA +
    // x-loads), stage(it+1), compute(it). 16 iters of K-step 256.
    STAGE(0, 0, A0a, A0b, A1a, A1b, A2a, A2b, A3a, A3b);
    for (int jj = 0; jj < 8; ++jj) {
        __syncthreads();
        STAGE(1, 2 * jj + 1, B0a, B0b, B1a, B1b, B2a, B2b, B3a, B3b);
        COMPUTE(0, A0a, A0b, A1a, A1b, A2a, A2b, A3a, A3b);
        __syncthreads();
        if (jj < 7)
            STAGE(0, 2 * jj + 2, A0a, A0b, A1a, A1b, A2a, A2b, A3a, A3b);
        COMPUTE(1, B0a, B0b, B1a, B1b, B2a, B2b, B3a, B3b);
    }
#undef STAGE
#undef COMPUTE
#undef GENSEL
#undef MFMA_

    // ---- epilogue: 4-way split-K reduce (verbatim R16), two fm-pair passes ----
    float* rbuf = (float*)POOL;      // 16384 floats; max used 4224+4221 = 8445
#pragma unroll
    for (int p = 0; p < 2; ++p) {
        __syncthreads();             // pass 0: everyone done with Bs; pass 1: prev done
        if (kk >= 2) {               // kk=2 -> slab 0, kk=3 -> slab 1
            float* s_ = rbuf + (size_t)(kk - 2) * 4224 + lane * 66;
#pragma unroll
            for (int fm = 0; fm < 2; ++fm)
#pragma unroll
                for (int fn = 0; fn < 2; ++fn)
#pragma unroll
                    for (int r = 0; r < 16; ++r)
                        s_[(fm * 2 + fn) * 16 + r] = acc[2 * p + fm][fn][r];
        }
        __syncthreads();
        if (kk < 2) {                // kk0 += kk2, kk1 += kk3
            const float* s_ = rbuf + (size_t)kk * 4224 + lane * 66;
#pragma unroll
            for (int fm = 0; fm < 2; ++fm)
#pragma unroll
                for (int fn = 0; fn < 2; ++fn)
#pragma unroll
                    for (int r = 0; r < 16; ++r)
                        acc[2 * p + fm][fn][r] += s_[(fm * 2 + fn) * 16 + r];
        }
        __syncthreads();
        if (kk == 1) {               // kk1 partial -> slab 0
            float* s_ = rbuf + lane * 66;
#pragma unroll
            for (int fm = 0; fm < 2; ++fm)
#pragma unroll
                for (int fn = 0; fn < 2; ++fn)
#pragma unroll
                    for (int r = 0; r < 16; ++r)
                        s_[(fm * 2 + fn) * 16 + r] = acc[2 * p + fm][fn][r];
        }
        __syncthreads();
        if (kk == 0) {
            const float* s_ = rbuf + lane * 66;
            // C/D layout (32x32): col = lane&31, row = (r&3)+8*(r>>2)+4*(lane>>5)
#pragma unroll
            for (int fn = 0; fn < 2; ++fn) {
                int o = o0 + fn * 32 + l31;
                float bv = bias[o];
#pragma unroll
                for (int fm = 0; fm < 2; ++fm) {
#pragma unroll
                    for (int r = 0; r < 16; ++r) {
                        float v = acc[2 * p + fm][fn][r] + s_[(fm * 2 + fn) * 16 + r] + bv;
                        int token = m0 + (2 * p + fm) * 32 + (r & 3) + 8 * (r >> 2) + 4 * half;
                        out[(size_t)token * OUT_FEAT + o] = v;
                    }
                }
            }
        }
    }
}

extern "C" void kernel_launch(void* const* d_in, const int* in_sizes, int n_in,
                              void* d_out, int out_size, void* d_ws, size_t ws_size,
                              hipStream_t stream) {
    const float* x            = (const float*)d_in[0];
    const float* coeff        = (const float*)d_in[1];
    const float* scale_base   = (const float*)d_in[2];
    const float* scale_spline = (const float*)d_in[3];
    const float* base_bias    = (const float*)d_in[4];
    float* out = (float*)d_out;

    short* Wb   = (short*)d_ws;                                  // 4 MB
    float* bias = (float*)((char*)d_ws + (size_t)OUT_FEAT * KDIM * 2);

    kan_prep<<<OUT_FEAT, 256, 0, stream>>>(coeff, scale_base, scale_spline, base_bias, Wb, bias);
    kan_gemm17<<<(NTOK / 128) * (OUT_FEAT / 64), 256, 0, stream>>>(x, Wb, bias, out);
}